// Round 10
// baseline (747.127 us; speedup 1.0000x reference)
//
#include <hip/hip_runtime.h>

#define EPS 1e-5f
#define KK 27

typedef __bf16 bf16x8 __attribute__((ext_vector_type(8)));
typedef float f32x4 __attribute__((ext_vector_type(4)));

__device__ __forceinline__ unsigned short f2bf(float f) {
    union { float f; unsigned u; } v; v.f = f;
    unsigned r = v.u + 0x7fffu + ((v.u >> 16) & 1u);  // round-to-nearest-even
    return (unsigned short)(r >> 16);
}
__device__ __forceinline__ float bf2f(unsigned short h) {
    union { unsigned u; float f; } v; v.u = ((unsigned)h) << 16; return v.f;
}

__device__ __forceinline__ f32x4 mfma16(bf16x8 a, bf16x8 b, f32x4 c) {
    return __builtin_amdgcn_mfma_f32_16x16x32_bf16(a, b, c, 0, 0, 0);
}

// ---------------- generic fills ----------------
__global__ void fill_i32(int* __restrict__ p, long tot, int val) {
    long i = (long)blockIdx.x * blockDim.x + threadIdx.x;
    if (i < tot) p[i] = val;
}

// ---------------- spatial sort by pool_seg (raster-order key) ----------------
__global__ void hist_kernel(const int* __restrict__ seg, int* __restrict__ bins, int n) {
    int i = blockIdx.x * 256 + threadIdx.x;
    if (i < n) atomicAdd(&bins[seg[i]], 1);
}

__global__ void scan_kernel(const int* __restrict__ bins, int* __restrict__ base, int nbins) {
    __shared__ int sums[1024];
    int t = threadIdx.x;
    int C = (nbins + 1023) >> 10;
    int lo = t * C, hi = lo + C < nbins ? lo + C : nbins;
    int s = 0;
    for (int i = lo; i < hi; ++i) s += bins[i];
    sums[t] = s;
    __syncthreads();
    for (int off = 1; off < 1024; off <<= 1) {
        int v = (t >= off) ? sums[t - off] : 0;
        __syncthreads();
        sums[t] += v;
        __syncthreads();
    }
    int run = (t > 0) ? sums[t - 1] : 0;
    for (int i = lo; i < hi; ++i) { int b = bins[i]; base[i] = run; run += b; }
}

__global__ void scatter_perm(const int* __restrict__ seg, const int* __restrict__ base,
                             int* __restrict__ cnt, int* __restrict__ perm,
                             const float* __restrict__ feats, float* __restrict__ featsP,
                             int* __restrict__ segP, int n) {
    int i = blockIdx.x * 256 + threadIdx.x;
    if (i >= n) return;
    int s = seg[i];
    int p = base[s] + atomicAdd(&cnt[s], 1);
    perm[i] = p;
    featsP[p] = feats[i];
    segP[p] = s;
}

// dense inverse map in PERMUTED row space: idxG[block][k][row&31]
__global__ void invert_map_perm(const int* __restrict__ km_in, const int* __restrict__ km_out,
                                const int* __restrict__ perm, int* __restrict__ idxG,
                                int M, int nrows) {
    long i = (long)blockIdx.x * blockDim.x + threadIdx.x;
    if (i >= (long)KK * M) return;
    int k = (int)(i / M);
    int ki = km_in[i];
    if (ki < nrows) {
        int ko = perm[km_out[i]];
        idxG[(long)(ko >> 5) * 1024 + k * 32 + (ko & 31)] = perm[ki];
    }
}

__global__ void invert_map_g(const int* __restrict__ km_in, const int* __restrict__ km_out,
                             int* __restrict__ idxG, int M, int nrows) {
    long i = (long)blockIdx.x * blockDim.x + threadIdx.x;
    if (i >= (long)KK * M) return;
    int k = (int)(i / M);
    int ki = km_in[i];
    if (ki < nrows) {
        int ko = km_out[i];
        idxG[(long)(ko >> 5) * 1024 + k * 32 + (ko & 31)] = ki;
    }
}

// ---------------- weight prep ----------------
// W[k][ci][co] f32 -> fragment-major bf16 halves:
// off = (((k*(Cout/16) + t)*2 + s)*64 + lane)*8 + j, lane = quad*16+m16.
__global__ void wt_frag(const float* __restrict__ W, unsigned short* __restrict__ Wt,
                        int Cin, int Cout) {
    long i = (long)blockIdx.x * blockDim.x + threadIdx.x;
    long tot = (long)KK * Cin * Cout;
    if (i >= tot) return;
    int k  = (int)(i / (Cin * Cout));
    int r  = (int)(i % (Cin * Cout));
    int ci = r / Cout, co = r % Cout;
    int t = co >> 4, m16 = co & 15;
    int s = ci >> 5, quad = (ci >> 3) & 3, j = ci & 7;
    int lane = quad * 16 + m16;
    long off = ((((long)k * (Cout >> 4) + t) * 2 + s) * 64 + lane) * 8 + j;
    Wt[off] = f2bf(W[i]);
}

__global__ void w1t_bf16(const float* __restrict__ W1, unsigned short* __restrict__ W1t) {
    int i = blockIdx.x * blockDim.x + threadIdx.x;
    if (i >= 64 * 32) return;
    int c = i / 32, kk = i % 32;
    W1t[i] = (kk < KK) ? f2bf(W1[kk * 64 + c]) : (unsigned short)0;
}

// ---------------- conv1 gather-MFMA (1->64), fused stats (permuted space) ----------------
__global__ __launch_bounds__(256, 2) void conv1_mfma(const float* __restrict__ feats,
                                                     const unsigned short* __restrict__ W1t,
                                                     const int* __restrict__ idxG, int n,
                                                     unsigned short* __restrict__ out,
                                                     float* __restrict__ st) {
    int wave = threadIdx.x >> 6, lane = threadIdx.x & 63;
    int m16 = lane & 15, quad = lane >> 4;
    long tile = (long)blockIdx.x * 4 + wave;
    long j0 = tile * 32;
    if (j0 >= n) return;
    int jm[2] = {(int)j0 + m16, (int)j0 + 16 + m16};

    int idx[2][8];
    #pragma unroll
    for (int i = 0; i < 8; ++i) {
        int kk = quad * 8 + i;
        bool kv = (kk < KK);
        #pragma unroll
        for (int t2 = 0; t2 < 2; ++t2)
            idx[t2][i] = kv ? idxG[(long)(jm[t2] >> 5) * 1024 + kk * 32 + (jm[t2] & 31)] : n;
    }
    float f[2][8];
    #pragma unroll
    for (int i = 0; i < 8; ++i)
        #pragma unroll
        for (int t2 = 0; t2 < 2; ++t2) {
            int r = idx[t2][i];
            f[t2][i] = (r < n) ? feats[r] : 0.f;
        }

    union { bf16x8 v; unsigned short s[8]; } a[2];
    #pragma unroll
    for (int t2 = 0; t2 < 2; ++t2)
        #pragma unroll
        for (int i = 0; i < 8; ++i) a[t2].s[i] = f2bf(f[t2][i]);

    f32x4 acc[2][4];
    #pragma unroll
    for (int t2 = 0; t2 < 2; ++t2)
        #pragma unroll
        for (int t = 0; t < 4; ++t) acc[t2][t] = (f32x4){0.f, 0.f, 0.f, 0.f};

    const unsigned short* wb = W1t + quad * 8;
    #pragma unroll
    for (int t = 0; t < 4; ++t) {
        bf16x8 b = *(const bf16x8*)(wb + (t * 16 + m16) * 32);
        acc[0][t] = mfma16(a[0].v, b, acc[0][t]);
        acc[1][t] = mfma16(a[1].v, b, acc[1][t]);
    }

    #pragma unroll
    for (int t2 = 0; t2 < 2; ++t2) {
        long row = j0 + t2 * 16 + quad * 4;
        #pragma unroll
        for (int t = 0; t < 4; ++t)
            #pragma unroll
            for (int r2 = 0; r2 < 4; ++r2) {
                long rr = row + r2;
                if (rr < n) out[rr * 64 + t * 16 + m16] = f2bf(acc[t2][t][r2]);
            }
    }
    #pragma unroll
    for (int t = 0; t < 4; ++t) {
        float s = 0.f, q = 0.f;
        #pragma unroll
        for (int t2 = 0; t2 < 2; ++t2)
            #pragma unroll
            for (int r2 = 0; r2 < 4; ++r2) { float v = acc[t2][t][r2]; s += v; q += v * v; }
        s += __shfl_xor(s, 16); q += __shfl_xor(q, 16);
        s += __shfl_xor(s, 32); q += __shfl_xor(q, 32);
        if (quad == 0) {
            atomicAdd(&st[t * 16 + m16], s);
            atomicAdd(&st[64 + t * 16 + m16], q);
        }
    }
}

// ---------------- BN+ReLU in place on bf16, 8-wide ----------------
__global__ void bnrelu1_vec(unsigned short* __restrict__ x, const float* __restrict__ stats,
                            const float* __restrict__ g, const float* __restrict__ be, long n) {
    __shared__ float sc[64], sh[64];
    int tid = threadIdx.x;
    if (tid < 64) {
        float mu  = stats[tid] / (float)n;
        float var = stats[64 + tid] / (float)n - mu * mu;
        float s   = g[tid] * rsqrtf(var + EPS);
        sc[tid] = s; sh[tid] = be[tid] - mu * s;
    }
    __syncthreads();
    long i = (long)blockIdx.x * 256 + tid;
    long tot = (n + 1) * 8;
    if (i >= tot) return;
    long j = i >> 3; int c0 = (int)(i & 7) * 8;
    union { bf16x8 v; unsigned short s[8]; } u, o;
    if (j < n) {
        u.v = *(const bf16x8*)(x + j * 64 + c0);
        #pragma unroll
        for (int t = 0; t < 8; ++t) {
            float f = bf2f(u.s[t]) * sc[c0 + t] + sh[c0 + t];
            o.s[t] = f2bf(f > 0.f ? f : 0.f);
        }
    } else {
        #pragma unroll
        for (int t = 0; t < 8; ++t) o.s[t] = 0;
    }
    *(bf16x8*)(x + j * 64 + c0) = o.v;
}

// ---------------- MFMA gather-conv: 8-wave blocks (256 rows share B), B in LDS dbuf ----------------
// WV waves x 32 rows; B staged cooperatively by all WV*64 threads (halves B
// segment traffic 4x vs 4-wave blocks). XCD-contiguous swizzle: consecutive
// logical blocks (sorted row ranges) land on the same XCD's L2.
template <int NT, int WV, bool BF16OUT>
__global__ __launch_bounds__(WV * 64, 2) void conv_mfma(const unsigned short* __restrict__ xin,
                                                        const unsigned short* __restrict__ Wt,
                                                        const int* __restrict__ idxG,
                                                        void* __restrict__ outv, int n,
                                                        float* __restrict__ st) {
    constexpr int COUT = NT * 16;
    constexpr int SLICE = COUT * 64 * 2;          // bytes per k-slice
    constexpr int ROUNDS = SLICE / (WV * 1024);   // per-thread 16B stages
    __shared__ __align__(16) int lidx[WV][1024];
    __shared__ __align__(16) char bbuf[2][SLICE];

    int tid = threadIdx.x;
    int wave = tid >> 6, lane = tid & 63;
    int m16 = lane & 15, quad = lane >> 4;
    int chunk = gridDim.x >> 3;
    int logical = (blockIdx.x & 7) * chunk + (blockIdx.x >> 3);
    long j0 = ((long)logical * WV + wave) * 32;
    bool valid = (j0 < n);
    long jb = valid ? (j0 >> 5) : 0;

    // stage this wave's 27x32 idx block (4KB, coalesced)
    {
        const int* src = idxG + jb * 1024;
        #pragma unroll
        for (int i = 0; i < 4; ++i)
            __builtin_amdgcn_global_load_lds(
                (const __attribute__((address_space(1))) unsigned*)(src + i * 256 + lane * 4),
                (__attribute__((address_space(3))) unsigned*)(&lidx[wave][i * 256]),
                16, 0, 0);
    }
    // stage B[0]
    {
        const char* src = (const char*)Wt;
        #pragma unroll
        for (int r = 0; r < ROUNDS; ++r)
            __builtin_amdgcn_global_load_lds(
                (const __attribute__((address_space(1))) unsigned*)(src + r * WV * 1024 + tid * 16),
                (__attribute__((address_space(3))) unsigned*)(&bbuf[0][r * WV * 1024 + wave * 1024 + lane * 16]),
                16, 0, 0);
    }
    __syncthreads();   // idx + B[0] resident

    const int* lip = &lidx[wave][m16];
    bf16x8 ab[2][2][2];   // [ring][t2][s]
    {
        int r0 = valid ? lip[0] : n, r1 = valid ? lip[16] : n;
        const unsigned short* a0 = xin + (long)r0 * 64 + quad * 8;
        const unsigned short* a1 = xin + (long)r1 * 64 + quad * 8;
        ab[0][0][0] = *(const bf16x8*)a0;
        ab[0][0][1] = *(const bf16x8*)(a0 + 32);
        ab[0][1][0] = *(const bf16x8*)a1;
        ab[0][1][1] = *(const bf16x8*)(a1 + 32);
    }

    f32x4 acc[2][NT];
    #pragma unroll
    for (int t2 = 0; t2 < 2; ++t2)
        #pragma unroll
        for (int t = 0; t < NT; ++t) acc[t2][t] = (f32x4){0.f, 0.f, 0.f, 0.f};

    #pragma unroll
    for (int k = 0; k < KK; ++k) {
        const int kb = k & 1;
        if (k + 1 < KK) {
            const char* src = (const char*)Wt + (long)(k + 1) * SLICE;
            #pragma unroll
            for (int r = 0; r < ROUNDS; ++r)
                __builtin_amdgcn_global_load_lds(
                    (const __attribute__((address_space(1))) unsigned*)(src + r * WV * 1024 + tid * 16),
                    (__attribute__((address_space(3))) unsigned*)(&bbuf[1 - kb][r * WV * 1024 + wave * 1024 + lane * 16]),
                    16, 0, 0);
            int r0 = valid ? lip[(k + 1) * 32] : n;
            int r1 = valid ? lip[(k + 1) * 32 + 16] : n;
            const unsigned short* a0 = xin + (long)r0 * 64 + quad * 8;
            const unsigned short* a1 = xin + (long)r1 * 64 + quad * 8;
            ab[1 - kb][0][0] = *(const bf16x8*)a0;
            ab[1 - kb][0][1] = *(const bf16x8*)(a0 + 32);
            ab[1 - kb][1][0] = *(const bf16x8*)a1;
            ab[1 - kb][1][1] = *(const bf16x8*)(a1 + 32);
        }
        #pragma unroll
        for (int s = 0; s < 2; ++s)
            #pragma unroll
            for (int t = 0; t < NT; ++t) {
                bf16x8 b = *(const bf16x8*)&bbuf[kb][((t * 2 + s) * 64 + lane) * 16];
                acc[0][t] = mfma16(ab[kb][0][s], b, acc[0][t]);
                acc[1][t] = mfma16(ab[kb][1][s], b, acc[1][t]);
            }
        if (k + 1 < KK) __syncthreads();
    }

    if (valid) {
        #pragma unroll
        for (int t2 = 0; t2 < 2; ++t2) {
            long row = j0 + t2 * 16 + quad * 4;    // D: col=m16, row=quad*4+reg
            #pragma unroll
            for (int t = 0; t < NT; ++t)
                #pragma unroll
                for (int r2 = 0; r2 < 4; ++r2) {
                    long rr = row + r2;
                    if (rr < n) {
                        long o = rr * COUT + t * 16 + m16;
                        if (BF16OUT) ((unsigned short*)outv)[o] = f2bf(acc[t2][t][r2]);
                        else         ((float*)outv)[o] = acc[t2][t][r2];
                    }
                }
        }
        #pragma unroll
        for (int t = 0; t < NT; ++t) {
            float s = 0.f, q = 0.f;
            #pragma unroll
            for (int t2 = 0; t2 < 2; ++t2)
                #pragma unroll
                for (int r2 = 0; r2 < 4; ++r2) { float v = acc[t2][t][r2]; s += v; q += v * v; }
            s += __shfl_xor(s, 16); q += __shfl_xor(q, 16);
            s += __shfl_xor(s, 32); q += __shfl_xor(q, 32);
            if (quad == 0) {
                atomicAdd(&st[t * 16 + m16], s);
                atomicAdd(&st[COUT + t * 16 + m16], q);
            }
        }
    }
}

// ---------------- BN+ReLU on bf16 x2 fused with segment-max pool ----------------
__global__ void pool_kernel(const unsigned short* __restrict__ x, const float* __restrict__ stats,
                            const float* __restrict__ g, const float* __restrict__ be,
                            const int* __restrict__ seg, long n, unsigned* __restrict__ pooled) {
    long j = (long)blockIdx.x * 4 + threadIdx.y;
    if (j >= n) return;
    int c = threadIdx.x;
    float mu  = stats[c] / (float)n;
    float var = stats[64 + c] / (float)n - mu * mu;
    float rs  = rsqrtf(var + EPS);
    float v   = g[c] * (bf2f(x[j * 64 + c]) - mu) * rs + be[c];
    if (v < 0.f) v = 0.f;
    atomicMax(&pooled[(long)seg[j] * 64 + c], __float_as_uint(v));
}

__global__ void pooled_bf16_vec(const unsigned* __restrict__ pooled, long np,
                                unsigned short* __restrict__ out) {
    long i = (long)blockIdx.x * 256 + threadIdx.x;
    long tot = (np + 1) * 8;
    if (i >= tot) return;
    long j = i >> 3; int c0 = (int)(i & 7) * 8;
    union { bf16x8 v; unsigned short s[8]; } o;
    if (j < np) {
        #pragma unroll
        for (int t = 0; t < 8; ++t)
            o.s[t] = f2bf(__uint_as_float(pooled[j * 64 + c0 + t]));
    } else {
        #pragma unroll
        for (int t = 0; t < 8; ++t) o.s[t] = 0;
    }
    *(bf16x8*)(out + j * 64 + c0) = o.v;
}

// ---------------- final BN+ReLU in place on d_out, float4 ----------------
__global__ void bnrelu_out_vec(float* __restrict__ x, const float* __restrict__ stats,
                               const float* __restrict__ g, const float* __restrict__ be,
                               long n) {
    __shared__ float sc[128], sh[128];
    int tid = threadIdx.x;
    if (tid < 128) {
        float mu  = stats[tid] / (float)n;
        float var = stats[128 + tid] / (float)n - mu * mu;
        float s   = g[tid] * rsqrtf(var + EPS);
        sc[tid] = s; sh[tid] = be[tid] - mu * s;
    }
    __syncthreads();
    long i = (long)blockIdx.x * 256 + tid;
    long tot = n * 32;
    if (i >= tot) return;
    int c0 = (int)(i & 31) * 4;
    float4 v = ((float4*)x)[i];
    v.x = v.x * sc[c0]     + sh[c0];     v.x = v.x > 0.f ? v.x : 0.f;
    v.y = v.y * sc[c0 + 1] + sh[c0 + 1]; v.y = v.y > 0.f ? v.y : 0.f;
    v.z = v.z * sc[c0 + 2] + sh[c0 + 2]; v.z = v.z > 0.f ? v.z : 0.f;
    v.w = v.w * sc[c0 + 3] + sh[c0 + 3]; v.w = v.w > 0.f ? v.w : 0.f;
    ((float4*)x)[i] = v;
}

extern "C" void kernel_launch(void* const* d_in, const int* in_sizes, int n_in,
                              void* d_out, int out_size, void* d_ws, size_t ws_size,
                              hipStream_t stream) {
    const float* feats = (const float*)d_in[0];
    const float* W1  = (const float*)d_in[1];
    const float* g1  = (const float*)d_in[3];
    const float* be1 = (const float*)d_in[4];
    const float* W2  = (const float*)d_in[5];
    const float* g2  = (const float*)d_in[7];
    const float* be2 = (const float*)d_in[8];
    const float* W3  = (const float*)d_in[9];
    const float* g3  = (const float*)d_in[11];
    const float* be3 = (const float*)d_in[12];
    const int* km_in   = (const int*)d_in[13];
    const int* km_out  = (const int*)d_in[14];
    const int* pool_seg = (const int*)d_in[15];
    const int* km2_in  = (const int*)d_in[16];
    const int* km2_out = (const int*)d_in[17];

    const int n  = in_sizes[0];           // 160000
    const int M  = in_sizes[13] / KK;
    const int np = out_size / 128;        // N_POOL
    const int M2 = in_sizes[16] / KK;
    const long nb1 = n / 32 + 2;
    const long nb2 = np / 32 + 2;

    // bias terms (b1/b2/b3) skipped: constant per-channel shift cancels through
    // training-mode BatchNorm exactly (mean-subtracted, variance unchanged).

    char* ws = (char*)d_ws;
    size_t off = 0;
    auto alloc = [&](size_t bytes) -> char* {
        char* p = ws + off;
        off += (bytes + 255) & ~(size_t)255;
        return p;
    };
    int* idxG1 = (int*)alloc(nb1 * 4096);
    int* idxG2 = (int*)alloc(nb2 * 4096);
    int* bins  = (int*)alloc((size_t)np * 4);
    int* base  = (int*)alloc((size_t)np * 4);
    int* cnt   = (int*)alloc((size_t)np * 4);
    int* perm  = (int*)alloc((size_t)n * 4);
    float* featsP = (float*)alloc((size_t)n * 4);
    int* segP  = (int*)alloc((size_t)n * 4);
    unsigned short* W1t = (unsigned short*)alloc(64 * 32 * 2);
    unsigned short* W2t = (unsigned short*)alloc((size_t)KK * 64 * 64 * 2);
    unsigned short* W3t = (unsigned short*)alloc((size_t)KK * 128 * 64 * 2);
    float* stats = (float*)alloc(4096);
    unsigned short* x1n = (unsigned short*)alloc((size_t)(n + 1) * 64 * 2);
    unsigned short* x2r = (unsigned short*)alloc((size_t)n * 64 * 2);
    unsigned* pooled = (unsigned*)alloc((size_t)np * 64 * 4);
    unsigned short* xpn = (unsigned short*)alloc((size_t)(np + 1) * 64 * 2);
    float* x3 = (float*)d_out;
    if (off > ws_size) return;

    float* stats1 = stats;
    float* stats2 = stats + 128;
    float* stats3 = stats + 256;

    hipMemsetAsync(stats, 0, 4096, stream);
    hipMemsetAsync(pooled, 0, (size_t)np * 64 * 4, stream);
    hipMemsetAsync(bins, 0, (size_t)np * 4, stream);
    hipMemsetAsync(cnt, 0, (size_t)np * 4, stream);

    // spatial sort: rows ordered by pool_seg (raster key)
    hist_kernel<<<(n + 255) / 256, 256, 0, stream>>>(pool_seg, bins, n);
    scan_kernel<<<1, 1024, 0, stream>>>(bins, base, np);
    scatter_perm<<<(n + 255) / 256, 256, 0, stream>>>(pool_seg, base, cnt, perm,
                                                      feats, featsP, segP, n);
    // maps
    {
        long t1 = nb1 * 1024;
        fill_i32<<<(int)((t1 + 255) / 256), 256, 0, stream>>>(idxG1, t1, n);
        long t2 = nb2 * 1024;
        fill_i32<<<(int)((t2 + 255) / 256), 256, 0, stream>>>(idxG2, t2, np);
        long e1 = (long)KK * M;
        invert_map_perm<<<(int)((e1 + 255) / 256), 256, 0, stream>>>(km_in, km_out, perm, idxG1, M, n);
        long e2 = (long)KK * M2;
        invert_map_g<<<(int)((e2 + 255) / 256), 256, 0, stream>>>(km2_in, km2_out, idxG2, M2, np);
    }
    {
        w1t_bf16<<<8, 256, 0, stream>>>(W1, W1t);
        long t2 = (long)KK * 64 * 64;
        wt_frag<<<(int)((t2 + 255) / 256), 256, 0, stream>>>(W2, W2t, 64, 64);
        long t3 = (long)KK * 64 * 128;
        wt_frag<<<(int)((t3 + 255) / 256), 256, 0, stream>>>(W3, W3t, 64, 128);
    }

    // layer 1 (+stats1 fused), permuted space
    {
        long waves = (n + 31) / 32;
        conv1_mfma<<<(int)((waves + 3) / 4), 256, 0, stream>>>(featsP, W1t, idxG1, n, x1n, stats1);
    }
    {
        long tot = ((long)(n + 1) * 8 + 255) / 256;
        bnrelu1_vec<<<(int)tot, 256, 0, stream>>>(x1n, stats1, g1, be1, n);
    }
    // layer 2 (+stats2 fused): 8-wave blocks, 256 rows, XCD-swizzled
    {
        long blocks = (n + 255) / 256;
        int grid = (int)(((blocks + 7) / 8) * 8);
        conv_mfma<4, 8, true><<<grid, 512, 0, stream>>>(x1n, W2t, idxG1, x2r, n, stats2);
    }
    pool_kernel<<<(n + 3) / 4, dim3(64, 4), 0, stream>>>(x2r, stats2, g2, be2, segP, n, pooled);
    {
        long tot = ((long)(np + 1) * 8 + 255) / 256;
        pooled_bf16_vec<<<(int)tot, 256, 0, stream>>>(pooled, np, xpn);
    }
    // layer 3 (+stats3 fused): 8-wave blocks, 256 rows, all 128 cols
    {
        long blocks = (np + 255) / 256;
        int grid = (int)(((blocks + 7) / 8) * 8);
        conv_mfma<8, 8, false><<<grid, 512, 0, stream>>>(xpn, W3t, idxG2, x3, np, stats3);
    }
    {
        long tot = ((long)np * 32 + 255) / 256;
        bnrelu_out_vec<<<(int)tot, 256, 0, stream>>>(x3, stats3, g3, be3, np);
    }
}

// Round 11
// 609.015 us; speedup vs baseline: 1.2268x; 1.2268x over previous
//
#include <hip/hip_runtime.h>

#define EPS 1e-5f
#define KK 27

typedef __bf16 bf16x8 __attribute__((ext_vector_type(8)));
typedef float f32x4 __attribute__((ext_vector_type(4)));

__device__ __forceinline__ unsigned short f2bf(float f) {
    union { float f; unsigned u; } v; v.f = f;
    unsigned r = v.u + 0x7fffu + ((v.u >> 16) & 1u);  // round-to-nearest-even
    return (unsigned short)(r >> 16);
}
__device__ __forceinline__ float bf2f(unsigned short h) {
    union { unsigned u; float f; } v; v.u = ((unsigned)h) << 16; return v.f;
}

__device__ __forceinline__ f32x4 mfma16(bf16x8 a, bf16x8 b, f32x4 c) {
    return __builtin_amdgcn_mfma_f32_16x16x32_bf16(a, b, c, 0, 0, 0);
}

// ---------------- map build: idxG[block][k][row&31] ----------------
__global__ void fill_i32(int* __restrict__ p, long tot, int val) {
    long i = (long)blockIdx.x * blockDim.x + threadIdx.x;
    if (i < tot) p[i] = val;
}

__global__ void invert_map_g(const int* __restrict__ km_in, const int* __restrict__ km_out,
                             int* __restrict__ idxG, int M, int nrows) {
    long i = (long)blockIdx.x * blockDim.x + threadIdx.x;
    if (i >= (long)KK * M) return;
    int k = (int)(i / M);
    int ki = km_in[i];
    if (ki < nrows) {
        int ko = km_out[i];
        idxG[(long)(ko >> 5) * 1024 + k * 32 + (ko & 31)] = ki;
    }
}

// ---------------- weight prep ----------------
// W[k][ci][co] f32 -> fragment-major bf16 halves:
// off = (((k*(Cout/16) + t)*2 + s)*64 + lane)*8 + j, lane = quad*16+m16,
// co = t*16+m16, ci = s*32+quad*8+j. Each (k,t,s) B-frag load = coalesced 1KB.
__global__ void wt_frag(const float* __restrict__ W, unsigned short* __restrict__ Wt,
                        int Cin, int Cout) {
    long i = (long)blockIdx.x * blockDim.x + threadIdx.x;
    long tot = (long)KK * Cin * Cout;
    if (i >= tot) return;
    int k  = (int)(i / (Cin * Cout));
    int r  = (int)(i % (Cin * Cout));
    int ci = r / Cout, co = r % Cout;
    int t = co >> 4, m16 = co & 15;
    int s = ci >> 5, quad = (ci >> 3) & 3, j = ci & 7;
    int lane = quad * 16 + m16;
    long off = ((((long)k * (Cout >> 4) + t) * 2 + s) * 64 + lane) * 8 + j;
    Wt[off] = f2bf(W[i]);
}

__global__ void w1t_bf16(const float* __restrict__ W1, unsigned short* __restrict__ W1t) {
    int i = blockIdx.x * blockDim.x + threadIdx.x;
    if (i >= 64 * 32) return;
    int c = i / 32, kk = i % 32;
    W1t[i] = (kk < KK) ? f2bf(W1[kk * 64 + c]) : (unsigned short)0;
}

// ---------------- conv1 gather-MFMA (1->64), fused stats ----------------
__global__ __launch_bounds__(256, 2) void conv1_mfma(const float* __restrict__ feats,
                                                     const unsigned short* __restrict__ W1t,
                                                     const int* __restrict__ idxG, int n,
                                                     unsigned short* __restrict__ out,
                                                     float* __restrict__ st) {
    int wave = threadIdx.x >> 6, lane = threadIdx.x & 63;
    int m16 = lane & 15, quad = lane >> 4;
    long tile = (long)blockIdx.x * 4 + wave;
    long j0 = tile * 32;
    if (j0 >= n) return;
    int jm[2] = {(int)j0 + m16, (int)j0 + 16 + m16};

    int idx[2][8];
    #pragma unroll
    for (int i = 0; i < 8; ++i) {
        int kk = quad * 8 + i;
        bool kv = (kk < KK);
        #pragma unroll
        for (int t2 = 0; t2 < 2; ++t2)
            idx[t2][i] = kv ? idxG[(long)(jm[t2] >> 5) * 1024 + kk * 32 + (jm[t2] & 31)] : n;
    }
    float f[2][8];
    #pragma unroll
    for (int i = 0; i < 8; ++i)
        #pragma unroll
        for (int t2 = 0; t2 < 2; ++t2) {
            int r = idx[t2][i];
            f[t2][i] = (r < n) ? feats[r] : 0.f;
        }

    union { bf16x8 v; unsigned short s[8]; } a[2];
    #pragma unroll
    for (int t2 = 0; t2 < 2; ++t2)
        #pragma unroll
        for (int i = 0; i < 8; ++i) a[t2].s[i] = f2bf(f[t2][i]);

    f32x4 acc[2][4];
    #pragma unroll
    for (int t2 = 0; t2 < 2; ++t2)
        #pragma unroll
        for (int t = 0; t < 4; ++t) acc[t2][t] = (f32x4){0.f, 0.f, 0.f, 0.f};

    const unsigned short* wb = W1t + quad * 8;
    #pragma unroll
    for (int t = 0; t < 4; ++t) {
        bf16x8 b = *(const bf16x8*)(wb + (t * 16 + m16) * 32);
        acc[0][t] = mfma16(a[0].v, b, acc[0][t]);
        acc[1][t] = mfma16(a[1].v, b, acc[1][t]);
    }

    #pragma unroll
    for (int t2 = 0; t2 < 2; ++t2) {
        long row = j0 + t2 * 16 + quad * 4;
        #pragma unroll
        for (int t = 0; t < 4; ++t)
            #pragma unroll
            for (int r2 = 0; r2 < 4; ++r2) {
                long rr = row + r2;
                if (rr < n) out[rr * 64 + t * 16 + m16] = f2bf(acc[t2][t][r2]);
            }
    }
    #pragma unroll
    for (int t = 0; t < 4; ++t) {
        float s = 0.f, q = 0.f;
        #pragma unroll
        for (int t2 = 0; t2 < 2; ++t2)
            #pragma unroll
            for (int r2 = 0; r2 < 4; ++r2) { float v = acc[t2][t][r2]; s += v; q += v * v; }
        s += __shfl_xor(s, 16); q += __shfl_xor(q, 16);
        s += __shfl_xor(s, 32); q += __shfl_xor(q, 32);
        if (quad == 0) {
            atomicAdd(&st[t * 16 + m16], s);
            atomicAdd(&st[64 + t * 16 + m16], q);
        }
    }
}

// ---------------- BN+ReLU in place on bf16, 8-wide ----------------
__global__ void bnrelu1_vec(unsigned short* __restrict__ x, const float* __restrict__ stats,
                            const float* __restrict__ g, const float* __restrict__ be, long n) {
    __shared__ float sc[64], sh[64];
    int tid = threadIdx.x;
    if (tid < 64) {
        float mu  = stats[tid] / (float)n;
        float var = stats[64 + tid] / (float)n - mu * mu;
        float s   = g[tid] * rsqrtf(var + EPS);
        sc[tid] = s; sh[tid] = be[tid] - mu * s;
    }
    __syncthreads();
    long i = (long)blockIdx.x * 256 + tid;
    long tot = (n + 1) * 8;
    if (i >= tot) return;
    long j = i >> 3; int c0 = (int)(i & 7) * 8;
    union { bf16x8 v; unsigned short s[8]; } u, o;
    if (j < n) {
        u.v = *(const bf16x8*)(x + j * 64 + c0);
        #pragma unroll
        for (int t = 0; t < 8; ++t) {
            float f = bf2f(u.s[t]) * sc[c0 + t] + sh[c0 + t];
            o.s[t] = f2bf(f > 0.f ? f : 0.f);
        }
    } else {
        #pragma unroll
        for (int t = 0; t < 8; ++t) o.s[t] = 0;
    }
    *(bf16x8*)(x + j * 64 + c0) = o.v;
}

// ---------------- MFMA gather-conv: wave-split-K, barrier-free K-loop ----------------
// Block = 4 waves, ALL on the same 32-row x 64-col tile; wave w covers offsets
// [7w, min(7w+7,27)) with a private accumulator -> no barriers in the K-loop,
// 4x independent gather streams per tile. Epilogue: acc -> LDS (stride 65),
// one barrier, cooperative 4-slot reduce + coalesced store + LDS-staged stats.
template <int CB, int CTOT, bool BF16OUT>
__global__ __launch_bounds__(256, 4) void conv_mfma(const unsigned short* __restrict__ xin,
                                                    const unsigned short* __restrict__ Wt,
                                                    const int* __restrict__ idxG,
                                                    void* __restrict__ outv, int n,
                                                    float* __restrict__ st) {
    constexpr int NT = 4;
    constexpr int TF = CTOT / 16;   // total 16-col frags across full Cout
    __shared__ __align__(16) int lidx[1024];
    __shared__ float accb[4][32 * 65];
    __shared__ float sst[128];

    int tid = threadIdx.x;
    int wave = tid >> 6, lane = tid & 63;
    int m16 = lane & 15, quad = lane >> 4;
    long w = blockIdx.x;
    long tile = w / CB;
    int colblk = (int)(w % CB);
    long j0 = tile * 32;

    // stage the tile's 27x32 idx block (4KB, coalesced, wave-uniform dest)
    __builtin_amdgcn_global_load_lds(
        (const __attribute__((address_space(1))) unsigned*)(idxG + tile * 1024 + tid * 4),
        (__attribute__((address_space(3))) unsigned*)(&lidx[tid * 4]), 16, 0, 0);
    if (tid < 128) sst[tid] = 0.f;
    __syncthreads();   // compiler's vmcnt(0) drain completes the idx stage

    const int* lip = lidx + m16;
    int kbeg = wave * 7;
    int kend = kbeg + 7 > KK ? KK : kbeg + 7;

    f32x4 acc[2][NT];
    #pragma unroll
    for (int t2 = 0; t2 < 2; ++t2)
        #pragma unroll
        for (int t = 0; t < NT; ++t) acc[t2][t] = (f32x4){0.f, 0.f, 0.f, 0.f};

    const unsigned short* xq = xin + quad * 8;
    const unsigned short* wl = Wt + (long)(colblk * NT * 2) * 512 + lane * 8;

    for (int k = kbeg; k < kend; ++k) {
        int r0 = lip[k * 32];
        int r1 = lip[k * 32 + 16];
        const unsigned short* a0 = xq + (long)r0 * 64;
        const unsigned short* a1 = xq + (long)r1 * 64;
        bf16x8 A[2][2];
        A[0][0] = *(const bf16x8*)a0;
        A[0][1] = *(const bf16x8*)(a0 + 32);
        A[1][0] = *(const bf16x8*)a1;
        A[1][1] = *(const bf16x8*)(a1 + 32);
        const unsigned short* wk = wl + (long)k * (TF * 1024);
        #pragma unroll
        for (int s = 0; s < 2; ++s)
            #pragma unroll
            for (int t = 0; t < NT; ++t) {
                bf16x8 b = *(const bf16x8*)(wk + t * 1024 + s * 512);
                acc[0][t] = mfma16(A[0][s], b, acc[0][t]);
                acc[1][t] = mfma16(A[1][s], b, acc[1][t]);
            }
    }

    // spill partial acc to LDS (stride-65 pad: conflict-light)
    #pragma unroll
    for (int t2 = 0; t2 < 2; ++t2)
        #pragma unroll
        for (int t = 0; t < NT; ++t)
            #pragma unroll
            for (int r2 = 0; r2 < 4; ++r2)
                accb[wave][(t2 * 16 + quad * 4 + r2) * 65 + t * 16 + m16] = acc[t2][t][r2];
    __syncthreads();

    // reduce 4 slots, write out (coalesced: 64 lanes = 64 consecutive cols), stats
    int c = tid & 63, rg = tid >> 6;
    float s = 0.f, q = 0.f;
    #pragma unroll
    for (int r2 = 0; r2 < 8; ++r2) {
        int r = rg * 8 + r2;
        float v = accb[0][r * 65 + c] + accb[1][r * 65 + c] +
                  accb[2][r * 65 + c] + accb[3][r * 65 + c];
        long rr = j0 + r;
        if (rr < n) {
            long o = rr * CTOT + colblk * 64 + c;
            if (BF16OUT) ((unsigned short*)outv)[o] = f2bf(v);
            else         ((float*)outv)[o] = v;
        }
        s += v; q += v * v;   // sentinel rows contribute exact zeros
    }
    atomicAdd(&sst[c], s);
    atomicAdd(&sst[64 + c], q);
    __syncthreads();
    if (tid < 64)       atomicAdd(&st[colblk * 64 + tid], sst[tid]);
    else if (tid < 128) atomicAdd(&st[CTOT + colblk * 64 + (tid - 64)], sst[tid]);
}

// ---------------- BN+ReLU on bf16 x2 fused with segment-max pool ----------------
__global__ void pool_kernel(const unsigned short* __restrict__ x, const float* __restrict__ stats,
                            const float* __restrict__ g, const float* __restrict__ be,
                            const int* __restrict__ seg, long n, unsigned* __restrict__ pooled) {
    long j = (long)blockIdx.x * 4 + threadIdx.y;
    if (j >= n) return;
    int c = threadIdx.x;
    float mu  = stats[c] / (float)n;
    float var = stats[64 + c] / (float)n - mu * mu;
    float rs  = rsqrtf(var + EPS);
    float v   = g[c] * (bf2f(x[j * 64 + c]) - mu) * rs + be[c];
    if (v < 0.f) v = 0.f;
    atomicMax(&pooled[(long)seg[j] * 64 + c], __float_as_uint(v));
}

__global__ void pooled_bf16_vec(const unsigned* __restrict__ pooled, long np,
                                unsigned short* __restrict__ out) {
    long i = (long)blockIdx.x * 256 + threadIdx.x;
    long tot = (np + 1) * 8;
    if (i >= tot) return;
    long j = i >> 3; int c0 = (int)(i & 7) * 8;
    union { bf16x8 v; unsigned short s[8]; } o;
    if (j < np) {
        #pragma unroll
        for (int t = 0; t < 8; ++t)
            o.s[t] = f2bf(__uint_as_float(pooled[j * 64 + c0 + t]));
    } else {
        #pragma unroll
        for (int t = 0; t < 8; ++t) o.s[t] = 0;
    }
    *(bf16x8*)(out + j * 64 + c0) = o.v;
}

// ---------------- final BN+ReLU in place on d_out, float4 ----------------
__global__ void bnrelu_out_vec(float* __restrict__ x, const float* __restrict__ stats,
                               const float* __restrict__ g, const float* __restrict__ be,
                               long n) {
    __shared__ float sc[128], sh[128];
    int tid = threadIdx.x;
    if (tid < 128) {
        float mu  = stats[tid] / (float)n;
        float var = stats[128 + tid] / (float)n - mu * mu;
        float s   = g[tid] * rsqrtf(var + EPS);
        sc[tid] = s; sh[tid] = be[tid] - mu * s;
    }
    __syncthreads();
    long i = (long)blockIdx.x * 256 + tid;
    long tot = n * 32;
    if (i >= tot) return;
    int c0 = (int)(i & 31) * 4;
    float4 v = ((float4*)x)[i];
    v.x = v.x * sc[c0]     + sh[c0];     v.x = v.x > 0.f ? v.x : 0.f;
    v.y = v.y * sc[c0 + 1] + sh[c0 + 1]; v.y = v.y > 0.f ? v.y : 0.f;
    v.z = v.z * sc[c0 + 2] + sh[c0 + 2]; v.z = v.z > 0.f ? v.z : 0.f;
    v.w = v.w * sc[c0 + 3] + sh[c0 + 3]; v.w = v.w > 0.f ? v.w : 0.f;
    ((float4*)x)[i] = v;
}

extern "C" void kernel_launch(void* const* d_in, const int* in_sizes, int n_in,
                              void* d_out, int out_size, void* d_ws, size_t ws_size,
                              hipStream_t stream) {
    const float* feats = (const float*)d_in[0];
    const float* W1  = (const float*)d_in[1];
    const float* g1  = (const float*)d_in[3];
    const float* be1 = (const float*)d_in[4];
    const float* W2  = (const float*)d_in[5];
    const float* g2  = (const float*)d_in[7];
    const float* be2 = (const float*)d_in[8];
    const float* W3  = (const float*)d_in[9];
    const float* g3  = (const float*)d_in[11];
    const float* be3 = (const float*)d_in[12];
    const int* km_in   = (const int*)d_in[13];
    const int* km_out  = (const int*)d_in[14];
    const int* pool_seg = (const int*)d_in[15];
    const int* km2_in  = (const int*)d_in[16];
    const int* km2_out = (const int*)d_in[17];

    const int n  = in_sizes[0];           // 160000
    const int M  = in_sizes[13] / KK;
    const int np = out_size / 128;        // N_POOL
    const int M2 = in_sizes[16] / KK;
    const long nb1 = n / 32 + 2;
    const long nb2 = np / 32 + 2;

    // bias terms (b1/b2/b3) skipped: constant per-channel shift cancels through
    // training-mode BatchNorm exactly (mean-subtracted, variance unchanged).

    char* ws = (char*)d_ws;
    size_t off = 0;
    auto alloc = [&](size_t bytes) -> char* {
        char* p = ws + off;
        off += (bytes + 255) & ~(size_t)255;
        return p;
    };
    int* idxG1 = (int*)alloc(nb1 * 4096);
    int* idxG2 = (int*)alloc(nb2 * 4096);
    unsigned short* W1t = (unsigned short*)alloc(64 * 32 * 2);
    unsigned short* W2t = (unsigned short*)alloc((size_t)KK * 64 * 64 * 2);
    unsigned short* W3t = (unsigned short*)alloc((size_t)KK * 128 * 64 * 2);
    float* stats = (float*)alloc(4096);
    unsigned short* x1n = (unsigned short*)alloc((size_t)(n + 1) * 64 * 2);
    unsigned short* x2r = (unsigned short*)alloc((size_t)n * 64 * 2);
    unsigned* pooled = (unsigned*)alloc((size_t)np * 64 * 4);
    unsigned short* xpn = (unsigned short*)alloc((size_t)(np + 1) * 64 * 2);
    float* x3 = (float*)d_out;
    if (off > ws_size) return;

    float* stats1 = stats;
    float* stats2 = stats + 128;
    float* stats3 = stats + 256;

    hipMemsetAsync(stats, 0, 4096, stream);
    hipMemsetAsync(pooled, 0, (size_t)np * 64 * 4, stream);

    {
        long t1 = nb1 * 1024;
        fill_i32<<<(int)((t1 + 255) / 256), 256, 0, stream>>>(idxG1, t1, n);
        long t2 = nb2 * 1024;
        fill_i32<<<(int)((t2 + 255) / 256), 256, 0, stream>>>(idxG2, t2, np);
        long e1 = (long)KK * M;
        invert_map_g<<<(int)((e1 + 255) / 256), 256, 0, stream>>>(km_in, km_out, idxG1, M, n);
        long e2 = (long)KK * M2;
        invert_map_g<<<(int)((e2 + 255) / 256), 256, 0, stream>>>(km2_in, km2_out, idxG2, M2, np);
    }
    {
        w1t_bf16<<<8, 256, 0, stream>>>(W1, W1t);
        long t2 = (long)KK * 64 * 64;
        wt_frag<<<(int)((t2 + 255) / 256), 256, 0, stream>>>(W2, W2t, 64, 64);
        long t3 = (long)KK * 64 * 128;
        wt_frag<<<(int)((t3 + 255) / 256), 256, 0, stream>>>(W3, W3t, 64, 128);
    }

    // layer 1 (+stats1 fused)
    {
        long waves = (n + 31) / 32;
        conv1_mfma<<<(int)((waves + 3) / 4), 256, 0, stream>>>(feats, W1t, idxG1, n, x1n, stats1);
    }
    {
        long tot = ((long)(n + 1) * 8 + 255) / 256;
        bnrelu1_vec<<<(int)tot, 256, 0, stream>>>(x1n, stats1, g1, be1, n);
    }
    // layer 2 (+stats2 fused): one block per 32-row tile, wave-split K
    {
        int tiles = (n + 31) / 32;
        conv_mfma<1, 64, true><<<tiles, 256, 0, stream>>>(x1n, W2t, idxG1, x2r, n, stats2);
    }
    pool_kernel<<<(n + 3) / 4, dim3(64, 4), 0, stream>>>(x2r, stats2, g2, be2, pool_seg, n, pooled);
    {
        long tot = ((long)(np + 1) * 8 + 255) / 256;
        pooled_bf16_vec<<<(int)tot, 256, 0, stream>>>(pooled, np, xpn);
    }
    // layer 3 (+stats3 fused): 2 column blocks per tile, wave-split K
    {
        int tiles = (np + 31) / 32;
        conv_mfma<2, 128, false><<<tiles * 2, 256, 0, stream>>>(xpn, W3t, idxG2, x3, np, stats3);
    }
    {
        long tot = ((long)np * 32 + 255) / 256;
        bnrelu_out_vec<<<(int)tot, 256, 0, stream>>>(x3, stats3, g3, be3, np);
    }
}